// Round 7
// baseline (314.597 us; speedup 1.0000x reference)
//
#include <hip/hip_runtime.h>

#define B_Q    1024
#define D_K    512
#define N_CLS  200
#define N_KEYS 50000
#define N_PAD  50048            // 391 * 128 (sorted keys, padded)
#define N_EXT  (N_PAD + 256)    // + 200 text rows + 56 zero rows
#define N_ZT   (N_PAD / 128)    // 391: first z-tile index

typedef __attribute__((ext_vector_type(8))) short bf16x8;
typedef __attribute__((ext_vector_type(4))) float f32x4;

__device__ __forceinline__ unsigned short f2bf(float f) {
  union { float f; unsigned int i; } v; v.f = f;
  unsigned int r = v.i + 0x7fffu + ((v.i >> 16) & 1u);
  return (unsigned short)(r >> 16);
}
__device__ __forceinline__ uint4 pack8(const float f[8], float s) {
  uint4 o;
  o.x = (unsigned)f2bf(f[0]*s) | ((unsigned)f2bf(f[1]*s) << 16);
  o.y = (unsigned)f2bf(f[2]*s) | ((unsigned)f2bf(f[3]*s) << 16);
  o.z = (unsigned)f2bf(f[4]*s) | ((unsigned)f2bf(f[5]*s) << 16);
  o.w = (unsigned)f2bf(f[6]*s) | ((unsigned)f2bf(f[7]*s) << 16);
  return o;
}
__device__ __forceinline__ void async_copy16(const void* g, void* lds) {
  __builtin_amdgcn_global_load_lds(
      (const __attribute__((address_space(1))) unsigned int*)g,
      (__attribute__((address_space(3))) unsigned int*)lds, 16, 0, 0);
}

// ---- histogram + (last block) exclusive scan fused: saves one launch ----
__global__ void k_histscan(const int* __restrict__ labels, int* __restrict__ hist,
                           int* __restrict__ cursor) {
  __shared__ int h[N_CLS];
  __shared__ int lastFlag;
  int t = threadIdx.x;
  if (t < N_CLS) h[t] = 0;
  __syncthreads();
  int n = blockIdx.x * 256 + t;
  if (n < N_KEYS) atomicAdd(&h[labels[n]], 1);
  __syncthreads();
  if (t < N_CLS && h[t]) atomicAdd(&hist[t], h[t]);
  __threadfence();
  if (t == 0) lastFlag = (atomicAdd(&hist[255], 1) == (int)gridDim.x - 1);
  __syncthreads();
  if (!lastFlag) return;
  // last block: all hist atomics are globally visible; scan into cursor
  __shared__ int s[N_CLS];
  int v = 0;
  if (t < N_CLS) { v = atomicAdd(&hist[t], 0); s[t] = v; }  // coherent read
  __syncthreads();
  for (int d = 1; d < N_CLS; d <<= 1) {
    int x = 0;
    if (t < N_CLS && t >= d) x = s[t - d];
    __syncthreads();
    if (t < N_CLS) s[t] += x;
    __syncthreads();
  }
  if (t < N_CLS) cursor[t] = s[t] - v;  // exclusive prefix
}

// Block-aggregated rank: dest[n] = sorted position of key n (coalesced write).
__global__ void k_perm(const int* __restrict__ labels, int* __restrict__ cursor,
                       int* __restrict__ dest) {
  __shared__ int lh[N_CLS];
  __shared__ int lbase[N_CLS];
  int t = threadIdx.x;
  if (t < N_CLS) lh[t] = 0;
  __syncthreads();
  int n = blockIdx.x * 256 + t;
  bool valid = (n < N_KEYS);
  int l = 0, lo = 0;
  if (valid) { l = labels[n]; lo = atomicAdd(&lh[l], 1); }
  __syncthreads();
  if (t < N_CLS && lh[t] > 0) lbase[t] = atomicAdd(&cursor[t], lh[t]);
  __syncthreads();
  if (valid) dest[n] = lbase[l] + lo;
}

// ---- fused prep: keys(stream-read, normalize, scatter-write sorted) + img
// ---- normalize -> qn + txt normalize -> kn tail + zero pad rows. Wave/row.
__global__ void k_prep2(const float* __restrict__ keys, const float* __restrict__ img,
                        const float* __restrict__ txt, const int* __restrict__ labels,
                        const int* __restrict__ dest, unsigned short* __restrict__ qn,
                        unsigned short* __restrict__ kn, int* __restrict__ cls) {
  int w = threadIdx.x >> 6, lane = threadIdx.x & 63;
  int row = blockIdx.x * 4 + w;
  const float* src; unsigned short* dst; int r;
  if (row < N_PAD) {
    if (row >= N_KEYS) {  // pad row: zero + sentinel
      *((uint4*)(kn + (size_t)row * D_K) + lane) = make_uint4(0, 0, 0, 0);
      if (lane == 0) cls[row] = N_CLS;
      return;
    }
    int d = dest[row];
    if (lane == 0) cls[d] = labels[row];
    src = keys + (size_t)row * D_K;
    dst = kn + (size_t)d * D_K;
  } else if (row < N_PAD + B_Q) {
    r = row - N_PAD;
    src = img + (size_t)r * D_K;
    dst = qn + (size_t)r * D_K;
  } else if (row < N_PAD + B_Q + N_CLS) {
    r = row - N_PAD - B_Q;
    src = txt + (size_t)r * D_K;
    dst = kn + (size_t)(N_PAD + r) * D_K;
  } else if (row < N_PAD + B_Q + N_CLS + 56) {
    r = N_PAD + N_CLS + (row - N_PAD - B_Q - N_CLS);  // zero tail rows
    *((uint4*)(kn + (size_t)r * D_K) + lane) = make_uint4(0, 0, 0, 0);
    return;
  } else return;
  const float4* s4 = (const float4*)src + lane * 2;
  float4 a = s4[0], b = s4[1];
  float f[8] = {a.x, a.y, a.z, a.w, b.x, b.y, b.z, b.w};
  float ss = 0.f;
#pragma unroll
  for (int i = 0; i < 8; i++) ss += f[i] * f[i];
#pragma unroll
  for (int d = 1; d < 64; d <<= 1) ss += __shfl_xor(ss, d);
  float rinv = rsqrtf(ss);
  *((uint4*)dst + lane) = pack8(f, rinv);
}

// ------- main MFMA GEMM: A double-buffered in LDS (2x16 KB), B direct
// ------- global->VGPR (L2/L3-hot, no barrier), one barrier per K-iter.
// B frag = contiguous 16 B of one kn row; quad-groups (lq 0..3) tile each
// row's 64 B line exactly -> efficient 16-line gather per instruction.
// The barrier's vmcnt drain waits only on A-copies issued one full iter ago.
// XOR source-column swizzle on A retained (round-5: conflicts -> 0).
__global__ __launch_bounds__(256, 3) void k_main(const unsigned short* __restrict__ qn,
                                                 const unsigned short* __restrict__ kn,
                                                 const int* __restrict__ cls,
                                                 float* __restrict__ out) {
  __shared__ unsigned short As[2][128 * 64];
  int t = threadIdx.x;
  int tileB = blockIdx.x, tileN = blockIdx.y;
  int rowB0 = tileB * 128, rowN0 = tileN * 128;

  f32x4 acc[4][4];
#pragma unroll
  for (int i = 0; i < 4; i++)
#pragma unroll
    for (int j = 0; j < 4; j++) acc[i][j] = (f32x4){0.f, 0.f, 0.f, 0.f};

  int lane = t & 63, w = t >> 6;
  int wr = (w >> 1) * 64, wc = (w & 1) * 64;
  int l15 = lane & 15, lq = lane >> 4;
  const int rA = t >> 3;                       // 0..31: row within 32-row chunk
  const int gsw = ((t & 7) ^ (rA & 7)) * 8;    // swizzled source col (shorts)
  const int sw = l15 & 7;                      // un-swizzle key for frag reads

  const unsigned short* bptr[4];
#pragma unroll
  for (int j = 0; j < 4; j++)
    bptr[j] = kn + (size_t)(rowN0 + wc + 16 * j + l15) * D_K + lq * 8;

  // prologue: stage A-slab 0 into buffer 0
#pragma unroll
  for (int i = 0; i < 4; i++)
    async_copy16(qn + (size_t)(rowB0 + i * 32 + rA) * D_K + gsw, &As[0][i * 2048 + t * 8]);

  for (int kt = 0; kt < 8; kt++) {
    int cur = kt & 1;
    __syncthreads();  // per-wave vmcnt drain => A(kt) landed; all waves synced
    if (kt < 7) {
      int k0n = (kt + 1) * 64;
#pragma unroll
      for (int i = 0; i < 4; i++)
        async_copy16(qn + (size_t)(rowB0 + i * 32 + rA) * D_K + k0n + gsw,
                     &As[cur ^ 1][i * 2048 + t * 8]);
    }
    int k0 = kt * 64;
#pragma unroll
    for (int ks = 0; ks < 64; ks += 32) {
      bf16x8 af[4], bf[4];
#pragma unroll
      for (int j = 0; j < 4; j++)
        bf[j] = *(const bf16x8*)(bptr[j] + k0 + ks);
#pragma unroll
      for (int i = 0; i < 4; i++)
        af[i] = *(const bf16x8*)&As[cur][(wr + 16 * i + l15) * 64 + ((((ks >> 3) + lq) ^ sw) * 8)];
#pragma unroll
      for (int i = 0; i < 4; i++)
#pragma unroll
        for (int j = 0; j < 4; j++)
          acc[i][j] = __builtin_amdgcn_mfma_f32_16x16x32_bf16(af[i], bf[j], acc[i][j], 0, 0, 0);
    }
  }

  if (tileN >= N_ZT) {
    // z-tile: out[row][col] += 0.5 * 100 * sim  (out pre-zeroed)
#pragma unroll
    for (int i = 0; i < 4; i++)
#pragma unroll
      for (int j = 0; j < 4; j++) {
        int col = rowN0 + wc + 16 * j + l15 - N_PAD;
        if (col < N_CLS) {
#pragma unroll
          for (int r = 0; r < 4; r++) {
            int row = rowB0 + wr + 16 * i + lq * 4 + r;
            atomicAdd(out + (size_t)row * N_CLS + col, 50.0f * acc[i][j][r]);
          }
        }
      }
    return;
  }

  // c-tile: aff = exp(5*sim); segment-sum over sorted classes; atomicAdd 0.5*sum
#pragma unroll
  for (int i = 0; i < 4; i++)
#pragma unroll
    for (int j = 0; j < 4; j++)
#pragma unroll
      for (int r = 0; r < 4; r++) acc[i][j][r] = __expf(5.0f * acc[i][j][r]);

  int cj[4];
#pragma unroll
  for (int j = 0; j < 4; j++) cj[j] = cls[rowN0 + wc + 16 * j + l15];
  int cseg0 = cls[rowN0 + wc];        // wave-uniform (sorted, nondecreasing)
  int cseg1 = cls[rowN0 + wc + 63];

  for (int c = cseg0; c <= cseg1; c++) {
    if (c >= N_CLS) break;  // pad sentinel; all later cols are pad too
#pragma unroll
    for (int i = 0; i < 4; i++) {
      float s0 = 0.f, s1 = 0.f, s2 = 0.f, s3 = 0.f;
#pragma unroll
      for (int j = 0; j < 4; j++) {
        if (cj[j] == c) {
          s0 += acc[i][j][0]; s1 += acc[i][j][1];
          s2 += acc[i][j][2]; s3 += acc[i][j][3];
        }
      }
#pragma unroll
      for (int d = 1; d < 16; d <<= 1) {
        s0 += __shfl_xor(s0, d); s1 += __shfl_xor(s1, d);
        s2 += __shfl_xor(s2, d); s3 += __shfl_xor(s3, d);
      }
      if (l15 == 0) {
        int row = rowB0 + wr + 16 * i + lq * 4;
        float* o = out + (size_t)row * N_CLS + c;
        if (s0 != 0.f) atomicAdd(o + 0 * N_CLS, 0.5f * s0);
        if (s1 != 0.f) atomicAdd(o + 1 * N_CLS, 0.5f * s1);
        if (s2 != 0.f) atomicAdd(o + 2 * N_CLS, 0.5f * s2);
        if (s3 != 0.f) atomicAdd(o + 3 * N_CLS, 0.5f * s3);
      }
    }
  }
}

extern "C" void kernel_launch(void* const* d_in, const int* in_sizes, int n_in,
                              void* d_out, int out_size, void* d_ws, size_t ws_size,
                              hipStream_t stream) {
  (void)in_sizes; (void)n_in; (void)out_size; (void)ws_size;
  const float* img    = (const float*)d_in[0];
  const float* txt    = (const float*)d_in[1];
  const float* keys   = (const float*)d_in[2];
  const int*   labels = (const int*)d_in[3];
  float*       out    = (float*)d_out;

  char* ws = (char*)d_ws;
  // workspace layout (bytes)
  unsigned short* qn = (unsigned short*)(ws + 0);         // 1024*512*2   = 1,048,576
  unsigned short* kn = (unsigned short*)(ws + 1048576);   // 50304*512*2  = 51,511,296
  int*  dest   = (int*)(ws + 52559872);                   // 50048*4
  int*  cls    = (int*)(ws + 52760064);                   // 50048*4
  int*  hist   = (int*)(ws + 52960256);                   // 256 ints (hist[255]=done ctr)
  int*  cursor = (int*)(ws + 52961280);                   // 256 ints

  hipMemsetAsync(hist, 0, 256 * sizeof(int), stream);
  hipMemsetAsync(out, 0, (size_t)B_Q * N_CLS * sizeof(float), stream);

  k_histscan<<<196, 256, 0, stream>>>(labels, hist, cursor);
  k_perm<<<196, 256, 0, stream>>>(labels, cursor, dest);
  k_prep2<<<(N_PAD + B_Q + N_CLS + 56 + 3) / 4, 256, 0, stream>>>(
      keys, img, txt, labels, dest, qn, kn, cls);
  k_main<<<dim3(B_Q / 128, N_ZT + 2), 256, 0, stream>>>(qn, kn, cls, out);
}

// Round 8
// 295.433 us; speedup vs baseline: 1.0649x; 1.0649x over previous
//
#include <hip/hip_runtime.h>

#define B_Q    1024
#define D_K    512
#define N_CLS  200
#define N_KEYS 50000
#define N_PAD  50048            // 391 * 128 (sorted keys, padded)
#define N_ZT   (N_PAD / 128)    // 391: first z-tile index

// prep2 row-range bounds
#define R0 N_PAD                // keys + pad rows -> kn
#define R1 (R0 + B_Q)           // img rows -> qn
#define R2 (R1 + N_CLS)         // txt rows -> kn tail
#define R3 (R2 + 56)            // zero kn tail rows
#define R4 (R3 + 400)           // zero d_out rows (400 * 2048B = 819200B)

typedef __attribute__((ext_vector_type(8))) short bf16x8;
typedef __attribute__((ext_vector_type(4))) float f32x4;

__device__ __forceinline__ unsigned short f2bf(float f) {
  union { float f; unsigned int i; } v; v.f = f;
  unsigned int r = v.i + 0x7fffu + ((v.i >> 16) & 1u);
  return (unsigned short)(r >> 16);
}
__device__ __forceinline__ uint4 pack8(const float f[8], float s) {
  uint4 o;
  o.x = (unsigned)f2bf(f[0]*s) | ((unsigned)f2bf(f[1]*s) << 16);
  o.y = (unsigned)f2bf(f[2]*s) | ((unsigned)f2bf(f[3]*s) << 16);
  o.z = (unsigned)f2bf(f[4]*s) | ((unsigned)f2bf(f[5]*s) << 16);
  o.w = (unsigned)f2bf(f[6]*s) | ((unsigned)f2bf(f[7]*s) << 16);
  return o;
}
__device__ __forceinline__ void async_copy16(const void* g, void* lds) {
  __builtin_amdgcn_global_load_lds(
      (const __attribute__((address_space(1))) unsigned int*)g,
      (__attribute__((address_space(3))) unsigned int*)lds, 16, 0, 0);
}

// ---- single-block counting sort: hist + scan + rank, all in LDS ----
// Writes only dest[n] (coalesced). Any within-class order is valid, so rank
// assignment via LDS atomics needs no stability. Replaces 2 kernels + memset.
__global__ __launch_bounds__(1024) void k_sort(const int* __restrict__ labels,
                                               int* __restrict__ dest) {
  __shared__ int hist[N_CLS];
  __shared__ int incl[N_CLS];
  __shared__ int cur[N_CLS];
  int t = threadIdx.x;
  if (t < N_CLS) hist[t] = 0;
  __syncthreads();
  for (int n = t; n < N_KEYS; n += 1024) atomicAdd(&hist[labels[n]], 1);
  __syncthreads();
  if (t < N_CLS) incl[t] = hist[t];
  __syncthreads();
  for (int d = 1; d < N_CLS; d <<= 1) {
    int x = 0;
    if (t < N_CLS && t >= d) x = incl[t - d];
    __syncthreads();
    if (t < N_CLS) incl[t] += x;
    __syncthreads();
  }
  if (t < N_CLS) cur[t] = incl[t] - hist[t];  // exclusive start
  __syncthreads();
  for (int n = t; n < N_KEYS; n += 1024)
    dest[n] = atomicAdd(&cur[labels[n]], 1);
}

// ---- fused prep: keys(stream-read, normalize, scatter-write sorted) + img
// ---- -> qn + txt -> kn tail + zero pads + ZERO d_out (replaces memset node).
__global__ void k_prep2(const float* __restrict__ keys, const float* __restrict__ img,
                        const float* __restrict__ txt, const int* __restrict__ labels,
                        const int* __restrict__ dest, unsigned short* __restrict__ qn,
                        unsigned short* __restrict__ kn, int* __restrict__ cls,
                        float* __restrict__ out) {
  int w = threadIdx.x >> 6, lane = threadIdx.x & 63;
  int row = blockIdx.x * 4 + w;
  const float* src; unsigned short* dst;
  if (row < R0) {
    if (row >= N_KEYS) {  // pad row: zero + sentinel
      *((uint4*)(kn + (size_t)row * D_K) + lane) = make_uint4(0, 0, 0, 0);
      if (lane == 0) cls[row] = N_CLS;
      return;
    }
    int d = dest[row];
    if (lane == 0) cls[d] = labels[row];
    src = keys + (size_t)row * D_K;
    dst = kn + (size_t)d * D_K;
  } else if (row < R1) {
    int r = row - R0;
    src = img + (size_t)r * D_K;
    dst = qn + (size_t)r * D_K;
  } else if (row < R2) {
    int r = row - R1;
    if (lane == 0) cls[N_PAD + r] = N_CLS;  // sentinel (epilogue prefetch safety)
    src = txt + (size_t)r * D_K;
    dst = kn + (size_t)(N_PAD + r) * D_K;
  } else if (row < R3) {
    int r = N_PAD + N_CLS + (row - R2);     // zero tail kn rows
    *((uint4*)(kn + (size_t)r * D_K) + lane) = make_uint4(0, 0, 0, 0);
    if (lane == 0) cls[r] = N_CLS;
    return;
  } else if (row < R4) {
    int zr = row - R3;                      // zero 2 KB of d_out per wave
    uint4* o4 = (uint4*)(out + (size_t)zr * 512) + lane * 2;
    o4[0] = make_uint4(0, 0, 0, 0);
    o4[1] = make_uint4(0, 0, 0, 0);
    return;
  } else return;
  const float4* s4 = (const float4*)src + lane * 2;
  float4 a = s4[0], b = s4[1];
  float f[8] = {a.x, a.y, a.z, a.w, b.x, b.y, b.z, b.w};
  float ss = 0.f;
#pragma unroll
  for (int i = 0; i < 8; i++) ss += f[i] * f[i];
#pragma unroll
  for (int d = 1; d < 64; d <<= 1) ss += __shfl_xor(ss, d);
  float rinv = rsqrtf(ss);
  *((uint4*)dst + lane) = pack8(f, rinv);
}

// ------- main MFMA GEMM (round-5 structure: single 32 KB LDS buffer, two
// barriers per K-iter, (256,3)) + fused z/c epilogues. XOR source swizzle
// keeps conflicts at 0. cls prefetched before K-loop (sentinels make it safe).
__global__ __launch_bounds__(256, 3) void k_main(const unsigned short* __restrict__ qn,
                                                 const unsigned short* __restrict__ kn,
                                                 const int* __restrict__ cls,
                                                 float* __restrict__ out) {
  __shared__ unsigned short As[128 * 64];
  __shared__ unsigned short Bs[128 * 64];
  int t = threadIdx.x;
  int tileB = blockIdx.x, tileN = blockIdx.y;
  int rowB0 = tileB * 128, rowN0 = tileN * 128;

  f32x4 acc[4][4];
#pragma unroll
  for (int i = 0; i < 4; i++)
#pragma unroll
    for (int j = 0; j < 4; j++) acc[i][j] = (f32x4){0.f, 0.f, 0.f, 0.f};

  int lane = t & 63, w = t >> 6;
  int wr = (w >> 1) * 64, wc = (w & 1) * 64;
  int l15 = lane & 15, lq = lane >> 4;
  const int rA = t >> 3;                       // 0..31: row within 32-row chunk
  const int gsw = ((t & 7) ^ (rA & 7)) * 8;    // swizzled source col (shorts)
  const int sw = l15 & 7;                      // un-swizzle key for frag reads

  // prefetch epilogue class metadata (latency hidden under the K-loop)
  int cj[4];
#pragma unroll
  for (int j = 0; j < 4; j++) cj[j] = cls[rowN0 + wc + 16 * j + l15];
  int cseg0 = cls[rowN0 + wc];
  int cseg1 = cls[rowN0 + wc + 63];

  for (int k0 = 0; k0 < D_K; k0 += 64) {
    __syncthreads();
#pragma unroll
    for (int i = 0; i < 4; i++) {
      int row = i * 32 + rA;
      async_copy16(qn + (size_t)(rowB0 + row) * D_K + k0 + gsw, &As[i * 2048 + t * 8]);
      async_copy16(kn + (size_t)(rowN0 + row) * D_K + k0 + gsw, &Bs[i * 2048 + t * 8]);
    }
    __syncthreads();
#pragma unroll
    for (int ks = 0; ks < 64; ks += 32) {
      bf16x8 af[4], bf[4];
#pragma unroll
      for (int i = 0; i < 4; i++)
        af[i] = *(const bf16x8*)&As[(wr + 16 * i + l15) * 64 + ((((ks >> 3) + lq) ^ sw) * 8)];
#pragma unroll
      for (int j = 0; j < 4; j++)
        bf[j] = *(const bf16x8*)&Bs[(wc + 16 * j + l15) * 64 + ((((ks >> 3) + lq) ^ sw) * 8)];
#pragma unroll
      for (int i = 0; i < 4; i++)
#pragma unroll
        for (int j = 0; j < 4; j++)
          acc[i][j] = __builtin_amdgcn_mfma_f32_16x16x32_bf16(af[i], bf[j], acc[i][j], 0, 0, 0);
    }
  }

  if (tileN >= N_ZT) {
    // z-tile: out[row][col] += 0.5 * 100 * sim  (out pre-zeroed by k_prep2)
#pragma unroll
    for (int i = 0; i < 4; i++)
#pragma unroll
      for (int j = 0; j < 4; j++) {
        int col = rowN0 + wc + 16 * j + l15 - N_PAD;
        if (col < N_CLS) {
#pragma unroll
          for (int r = 0; r < 4; r++) {
            int row = rowB0 + wr + 16 * i + lq * 4 + r;
            atomicAdd(out + (size_t)row * N_CLS + col, 50.0f * acc[i][j][r]);
          }
        }
      }
    return;
  }

  // c-tile: aff = exp(5*sim); segment-sum over sorted classes; atomicAdd 0.5*sum
#pragma unroll
  for (int i = 0; i < 4; i++)
#pragma unroll
    for (int j = 0; j < 4; j++)
#pragma unroll
      for (int r = 0; r < 4; r++) acc[i][j][r] = __expf(5.0f * acc[i][j][r]);

  for (int c = cseg0; c <= cseg1; c++) {
    if (c >= N_CLS) break;  // pad sentinel; all later cols are pad too
#pragma unroll
    for (int i = 0; i < 4; i++) {
      float s0 = 0.f, s1 = 0.f, s2 = 0.f, s3 = 0.f;
#pragma unroll
      for (int j = 0; j < 4; j++) {
        if (cj[j] == c) {
          s0 += acc[i][j][0]; s1 += acc[i][j][1];
          s2 += acc[i][j][2]; s3 += acc[i][j][3];
        }
      }
#pragma unroll
      for (int d = 1; d < 16; d <<= 1) {
        s0 += __shfl_xor(s0, d); s1 += __shfl_xor(s1, d);
        s2 += __shfl_xor(s2, d); s3 += __shfl_xor(s3, d);
      }
      if (l15 == 0) {
        int row = rowB0 + wr + 16 * i + lq * 4;
        float* o = out + (size_t)row * N_CLS + c;
        if (s0 != 0.f) atomicAdd(o + 0 * N_CLS, 0.5f * s0);
        if (s1 != 0.f) atomicAdd(o + 1 * N_CLS, 0.5f * s1);
        if (s2 != 0.f) atomicAdd(o + 2 * N_CLS, 0.5f * s2);
        if (s3 != 0.f) atomicAdd(o + 3 * N_CLS, 0.5f * s3);
      }
    }
  }
}

extern "C" void kernel_launch(void* const* d_in, const int* in_sizes, int n_in,
                              void* d_out, int out_size, void* d_ws, size_t ws_size,
                              hipStream_t stream) {
  (void)in_sizes; (void)n_in; (void)out_size; (void)ws_size;
  const float* img    = (const float*)d_in[0];
  const float* txt    = (const float*)d_in[1];
  const float* keys   = (const float*)d_in[2];
  const int*   labels = (const int*)d_in[3];
  float*       out    = (float*)d_out;

  char* ws = (char*)d_ws;
  // workspace layout (bytes)
  unsigned short* qn = (unsigned short*)(ws + 0);         // 1024*512*2   = 1,048,576
  unsigned short* kn = (unsigned short*)(ws + 1048576);   // 50304*512*2  = 51,511,296
  int*  dest = (int*)(ws + 52559872);                     // 50048*4
  int*  cls  = (int*)(ws + 52760064);                     // 50304*4 -> end 52,961,280

  // 3 graph nodes total (launch overhead ~10-15 us/node was the aux whale)
  k_sort<<<1, 1024, 0, stream>>>(labels, dest);
  k_prep2<<<(R4 + 3) / 4, 256, 0, stream>>>(keys, img, txt, labels, dest, qn, kn, cls, out);
  k_main<<<dim3(B_Q / 128, N_ZT + 2), 256, 0, stream>>>(qn, kn, cls, out);
}